// Round 13
// baseline (152.642 us; speedup 1.0000x reference)
//
#include <hip/hip_runtime.h>
#include <stdint.h>

typedef unsigned short u16;
typedef __attribute__((ext_vector_type(8))) short short8;
typedef __attribute__((ext_vector_type(4))) float f32x4;

#define B_      16
#define L_      1024
#define H_      1024
#define G_      128
#define M_TOT   16368            // B*(L-1)
#define OUT_SEG 2095104          // M_TOT*G_
#define KL_IDX  (4*OUT_SEG)
#define KL_BLOCKS 4092           // M_TOT / 4 exactly

// ws layout
#define WS_WT12_OFF  0           // bf16 [1024][1024] = 2,097,152 B
#define WS_W3T_OFF   2097152     // bf16 [256][1024]  =   524,288 B
#define WS_BIAS_OFF  2621440     // float[512]
#define WS_PART_OFF  2623488     // float[4092]

__device__ inline u16 f2bf(float f) {
    union { float f; uint32_t u; } x; x.f = f;
    uint32_t u = x.u;
    return (u16)((u + 0x7fffu + ((u >> 16) & 1u)) >> 16);
}

__device__ inline void gload16(const void* g, void* l) {
    __builtin_amdgcn_global_load_lds(
        (const __attribute__((address_space(1))) void*)g,
        (__attribute__((address_space(3))) void*)l, 16, 0, 0);
}

// ---------------- prep: WT12 bf16 [1024][1024], W3T bf16 [256][1024], bias ---
__global__ __launch_bounds__(256) void prep_kernel(
    const float* __restrict__ Wzm, const float* __restrict__ bzm,
    const float* __restrict__ Wzv, const float* __restrict__ bzv,
    const float* __restrict__ Wqm, const float* __restrict__ bqm,
    const float* __restrict__ Wqv, const float* __restrict__ bqv,
    u16* __restrict__ wt12, u16* __restrict__ w3t, float* __restrict__ bias)
{
    int n = blockIdx.x;
    int tid = threadIdx.x;
    if (n < 1024) {
        int half = n >> 9;           // 0: k in [0,1024), 1: [1024,2048)
        int np   = n & 511;
        const float* W; const float* bsrc; int g;
        if (np < 128)      { W = Wzm; bsrc = bzm; g = np; }
        else if (np < 256) { W = Wzv; bsrc = bzv; g = np - 128; }
        else if (np < 384) { W = Wqm; bsrc = bqm; g = np - 256; }
        else               { W = Wqv; bsrc = bqv; g = np - 384; }
        if (half == 0 && tid == 0) bias[np] = bsrc[g];
        #pragma unroll
        for (int i = 0; i < 4; ++i) {
            int k = i * 256 + tid;
            wt12[(size_t)n * 1024 + k] =
                f2bf(W[(size_t)(half * 1024 + k) * G_ + g]);
        }
    } else {
        int n2 = n - 1024;           // 0..255
        const float* W = (n2 < 128) ? Wqm : Wqv;
        int g = n2 & 127;
        #pragma unroll
        for (int i = 0; i < 4; ++i) {
            int k = i * 256 + tid;
            w3t[(size_t)n2 * 1024 + k] =
                f2bf(W[(size_t)(2048 + k) * G_ + g]);
        }
    }
}

// ---------------- GEMM + combine ---------------------------------------------
// Split-N layout (R12, verified): block = 128 event rows [e0,e0+128),
// e0 = mt*127; 128 vcols: v<64 -> H1 col nbg*64+v, v>=64 -> H2 col.
// 4 waves 2x2 of 64x64, BK=32. Loop1 (32): events x WT12. Loop2 (nbg>=4, 32):
// contexts x W3T into the wn==0 accs. Epilogue: H2 -> LDS, combine with +1 row.
// A: reg-staged fp32 -> cvt_pk bf16 -> swizzled ds_write_b128 (R6, verified).
// B: global_load_lds source-preswizzled (R12, verified).
// LDS/buf = 8KB A + 8KB B; 36KB total -> 4 blocks/CU.
// A/B swizzle (4 slots of 16B per 64B row): slot ^= (row>>1)&3.
__global__ __launch_bounds__(256, 4) void gemm_kernel(
    const float* __restrict__ events, const float* __restrict__ contexts,
    const u16* __restrict__ wt12, const u16* __restrict__ w3t,
    const float* __restrict__ bias, float* __restrict__ out)
{
    __shared__ __align__(16) char lds[36864];
#define ABUF(b) ((u16*)(lds + (b) * 8192))
#define BBUF(b) ((u16*)(lds + 16384 + (b) * 8192))

    const int tid = threadIdx.x;
    const int nbg = blockIdx.x / 136;          // 136 = 17*8: same-mt blocks
    const int mt  = blockIdx.x - nbg * 136;    // share bid%8 -> same XCD
    if (mt >= 129) return;
    const int e0  = mt * 127;

    const int lane = tid & 63;
    const int w    = tid >> 6;
    const int wm   = (w >> 1) * 64;
    const int wn   = (w & 1) * 64;
    const int lr   = lane & 15;
    const int kg   = lane >> 4;

    // ---- A staging: thread -> row r=tid>>1, half h=tid&1 (16 floats) ----
    const int r = tid >> 1;
    const int h = tid & 1;
    const int e = e0 + r;                       // <= 16383, always valid
    int p = e - (e >> 10);
    if (p > M_TOT - 1) p = M_TOT - 1;           // clamp (row is output-skipped)
    const float* evp  = events   + (size_t)e * 1024 + h * 16;
    const float* ctxp = contexts + (size_t)p * 1024 + h * 16;
    // swizzled LDS u16 indices for the 2 ds_write_b128 of this thread
    const int swr0 = r * 32 + ((((h << 1) + 0) ^ ((r >> 1) & 3)) << 3);
    const int swr1 = r * 32 + ((((h << 1) + 1) ^ ((r >> 1) & 3)) << 3);

    // ---- B1 staging: 2 chunks/thread; c -> vrow=c>>2, ss=(c&3)^((v>>1)&3)
    const u16* b1[2];
    #pragma unroll
    for (int it = 0; it < 2; ++it) {
        int c  = it * 256 + tid;
        int v  = c >> 2;
        int ss = (c & 3) ^ ((v >> 1) & 3);
        int sr = (v < 64) ? (nbg * 64 + v) : (512 + nbg * 64 + (v - 64));
        b1[it] = wt12 + (size_t)sr * 1024 + ss * 8;
    }
    // ---- B2 staging (loop2): 1 chunk/thread over 64 rows
    const int v2  = tid >> 2;
    const int ss2 = (tid & 3) ^ ((v2 >> 1) & 3);
    const int nb2 = (nbg >= 4) ? (nbg - 4) : 0;
    const u16* b2 = w3t + (size_t)(nb2 * 64 + v2) * 1024 + ss2 * 8;

    // ---- fragment read offsets (u16, swizzled) ----
    int aoff[4], boff[4];
    #pragma unroll
    for (int i = 0; i < 4; ++i) {
        int row = wm + i * 16 + lr;
        aoff[i] = row * 32 + ((kg ^ ((row >> 1) & 3)) << 3);
        int nn  = wn + i * 16 + lr;
        boff[i] = nn * 32 + ((kg ^ ((nn >> 1) & 3)) << 3);
    }

    f32x4 acc[4][4];
    #pragma unroll
    for (int i = 0; i < 4; ++i)
        #pragma unroll
        for (int j = 0; j < 4; ++j)
            acc[i][j] = (f32x4){0.f, 0.f, 0.f, 0.f};

    auto stageB1 = [&](int buf, int kt) {
        int k0 = kt * 32;
        #pragma unroll
        for (int it = 0; it < 2; ++it)
            gload16(b1[it] + k0, BBUF(buf) + (it * 256 + tid) * 8);
    };
    auto stageB2 = [&](int buf, int kt) {
        gload16(b2 + kt * 32, BBUF(buf) + tid * 8);
    };
    auto compute = [&](int buf) {
        const u16* Ab = ABUF(buf);
        const u16* Bb = BBUF(buf);
        short8 a[4], bf[4];
        #pragma unroll
        for (int i = 0; i < 4; ++i)
            a[i] = *(const short8*)&Ab[aoff[i]];
        #pragma unroll
        for (int j = 0; j < 4; ++j)
            bf[j] = *(const short8*)&Bb[boff[j]];
        __builtin_amdgcn_s_setprio(1);
        #pragma unroll
        for (int i = 0; i < 4; ++i)
            #pragma unroll
            for (int j = 0; j < 4; ++j)
                acc[i][j] = __builtin_amdgcn_mfma_f32_16x16x32_bf16(
                    a[i], bf[j], acc[i][j], 0, 0, 0);
        __builtin_amdgcn_s_setprio(0);
    };

    // Named A-staging registers (R6 pattern: no arrays, no scratch)
    f32x4 P0, P1, P2, P3;

#define LOADA(SRC, KT)                                                         \
    {                                                                          \
        const float* s_ = (SRC) + (KT) * 32;                                   \
        P0 = *(const f32x4*)(s_ +  0);                                         \
        P1 = *(const f32x4*)(s_ +  4);                                         \
        P2 = *(const f32x4*)(s_ +  8);                                         \
        P3 = *(const f32x4*)(s_ + 12);                                         \
    }
#define CVTW(BUF)                                                              \
    {                                                                          \
        union { short8 v; uint32_t u[4]; } w0_, w1_;                           \
        asm("v_cvt_pk_bf16_f32 %0, %1, %2" : "=v"(w0_.u[0]) : "v"(P0[0]), "v"(P0[1])); \
        asm("v_cvt_pk_bf16_f32 %0, %1, %2" : "=v"(w0_.u[1]) : "v"(P0[2]), "v"(P0[3])); \
        asm("v_cvt_pk_bf16_f32 %0, %1, %2" : "=v"(w0_.u[2]) : "v"(P1[0]), "v"(P1[1])); \
        asm("v_cvt_pk_bf16_f32 %0, %1, %2" : "=v"(w0_.u[3]) : "v"(P1[2]), "v"(P1[3])); \
        asm("v_cvt_pk_bf16_f32 %0, %1, %2" : "=v"(w1_.u[0]) : "v"(P2[0]), "v"(P2[1])); \
        asm("v_cvt_pk_bf16_f32 %0, %1, %2" : "=v"(w1_.u[1]) : "v"(P2[2]), "v"(P2[3])); \
        asm("v_cvt_pk_bf16_f32 %0, %1, %2" : "=v"(w1_.u[2]) : "v"(P3[0]), "v"(P3[1])); \
        asm("v_cvt_pk_bf16_f32 %0, %1, %2" : "=v"(w1_.u[3]) : "v"(P3[2]), "v"(P3[3])); \
        *(short8*)&ABUF(BUF)[swr0] = w0_.v;                                    \
        *(short8*)&ABUF(BUF)[swr1] = w1_.v;                                    \
    }

    // ---- loop 1: events x WT12 (32 steps) ----
    LOADA(evp, 0);
    stageB1(0, 0);
    CVTW(0);
    __syncthreads();
    int cur = 0;
    for (int kt = 0; kt < 32; ++kt) {
        if (kt + 1 < 32) {
            LOADA(evp, kt + 1);
            stageB1(cur ^ 1, kt + 1);
        }
        compute(cur);
        if (kt + 1 < 32) CVTW(cur ^ 1);
        __syncthreads();
        cur ^= 1;
    }

    // ---- loop 2: contexts x W3T into the wn==0 accumulators ----
    if (nbg >= 4) {
        LOADA(ctxp, 0);
        stageB2(0, 0);
        CVTW(0);
        __syncthreads();
        cur = 0;
        for (int kt = 0; kt < 32; ++kt) {
            if (kt + 1 < 32) {
                LOADA(ctxp, kt + 1);
                stageB2(cur ^ 1, kt + 1);
            }
            if (wn == 0) compute(cur);
            if (kt + 1 < 32) CVTW(cur ^ 1);
            __syncthreads();
            cur ^= 1;
        }
    }
#undef LOADA
#undef CVTW

    // ---- epilogue: bounce H2 through LDS, combine, store ----
    float* h2lds = (float*)lds;                 // [128][68] = 34816 B
    __syncthreads();
    if (wn == 64) {
        #pragma unroll
        for (int i = 0; i < 4; ++i)
            #pragma unroll
            for (int j = 0; j < 4; ++j)
                #pragma unroll
                for (int rr = 0; rr < 4; ++rr) {
                    int rq = wm + i * 16 + kg * 4 + rr;
                    h2lds[rq * 68 + j * 16 + lr] = acc[i][j][rr];
                }
    }
    __syncthreads();
    if (wn == 0) {
        #pragma unroll
        for (int j = 0; j < 4; ++j) {
            int gcol = nbg * 64 + j * 16 + lr;
            int seg  = gcol >> 7;
            int col  = gcol & 127;
            float bv = bias[gcol];
            float* obase = out + (size_t)seg * OUT_SEG + col;
            #pragma unroll
            for (int i = 0; i < 4; ++i) {
                #pragma unroll
                for (int rr = 0; rr < 4; ++rr) {
                    int rq = wm + i * 16 + kg * 4 + rr;
                    if (rq == 127) continue;
                    int ee = e0 + rq;
                    if ((ee & 1023) == 1023) continue;
                    int pp = ee - (ee >> 10);
                    obase[(size_t)pp * G_] =
                        acc[i][j][rr] + h2lds[(rq + 1) * 68 + j * 16 + lr] + bv;
                }
            }
        }
    }
#undef ABUF
#undef BBUF
}

// ---------------- KL reduction: stage 1 --------------------------------------
__global__ __launch_bounds__(256) void kl_kernel(const float* __restrict__ out,
                                                 float* __restrict__ partial)
{
    int wid  = threadIdx.x >> 6;
    int row  = blockIdx.x * 4 + wid;        // M_TOT = 4092*4 exactly
    int lane = threadIdx.x & 63;
    const float* zm  = out;
    const float* zlv = out + OUT_SEG;
    const float* qm  = out + (size_t)2 * OUT_SEG;
    const float* qlv = out + (size_t)3 * OUT_SEG;
    size_t base = (size_t)row * G_;
    float s = 0.f;
    #pragma unroll
    for (int hh = 0; hh < 2; ++hh) {
        int g = lane + hh * 64;
        float a = zm[base + g], b = zlv[base + g];
        float c = qm[base + g], d = qlv[base + g];
        float diff = a - c;
        s += d - b + (__expf(b) + diff * diff) * __expf(-d) - 1.0f;
    }
    #pragma unroll
    for (int off = 32; off > 0; off >>= 1)
        s += __shfl_down(s, off);
    __shared__ float pw[4];
    if (lane == 0) pw[wid] = s;
    __syncthreads();
    if (threadIdx.x == 0)
        partial[blockIdx.x] = pw[0] + pw[1] + pw[2] + pw[3];
}

// ---------------- KL reduction: stage 2 --------------------------------------
__global__ __launch_bounds__(256) void kl_final(const float* __restrict__ partial,
                                                float* __restrict__ out)
{
    float s = 0.f;
    for (int i = threadIdx.x; i < KL_BLOCKS; i += 256) s += partial[i];
    #pragma unroll
    for (int off = 32; off > 0; off >>= 1)
        s += __shfl_down(s, off);
    __shared__ float pw[4];
    int wid = threadIdx.x >> 6;
    int lane = threadIdx.x & 63;
    if (lane == 0) pw[wid] = s;
    __syncthreads();
    if (threadIdx.x == 0)
        out[KL_IDX] = 0.5f * (pw[0] + pw[1] + pw[2] + pw[3]) / (float)M_TOT;
}

// ---------------- launcher ----------------------------------------------------
extern "C" void kernel_launch(void* const* d_in, const int* in_sizes, int n_in,
                              void* d_out, int out_size, void* d_ws, size_t ws_size,
                              hipStream_t stream)
{
    const float* events   = (const float*)d_in[0];
    const float* contexts = (const float*)d_in[1];
    const float* Wzm = (const float*)d_in[2];
    const float* bzm = (const float*)d_in[3];
    const float* Wzv = (const float*)d_in[4];
    const float* bzv = (const float*)d_in[5];
    const float* Wqm = (const float*)d_in[6];
    const float* bqm = (const float*)d_in[7];
    const float* Wqv = (const float*)d_in[8];
    const float* bqv = (const float*)d_in[9];
    float* out = (float*)d_out;

    u16*   wt12    = (u16*)((char*)d_ws + WS_WT12_OFF);
    u16*   w3t     = (u16*)((char*)d_ws + WS_W3T_OFF);
    float* bias    = (float*)((char*)d_ws + WS_BIAS_OFF);
    float* partial = (float*)((char*)d_ws + WS_PART_OFF);

    prep_kernel<<<1280, 256, 0, stream>>>(Wzm, bzm, Wzv, bzv, Wqm, bqm,
                                          Wqv, bqv, wt12, w3t, bias);
    gemm_kernel<<<1088, 256, 0, stream>>>(events, contexts, wt12, w3t,
                                          bias, out);
    kl_kernel<<<KL_BLOCKS, 256, 0, stream>>>(out, partial);
    kl_final<<<1, 256, 0, stream>>>(partial, out);
}